// Round 13
// baseline (11650.455 us; speedup 1.0000x reference)
//
#include <hip/hip_runtime.h>

typedef __attribute__((ext_vector_type(4))) float f32x4;
typedef __attribute__((ext_vector_type(8))) short short8;
typedef __attribute__((ext_vector_type(4))) short short4_t;

__device__ __forceinline__ short f2bf(float f) {
  unsigned u = __float_as_uint(f);
  u += 0x7fffu + ((u >> 16) & 1u);   // round-to-nearest-even
  return (short)(u >> 16);
}

__device__ __forceinline__ float tanh_fast(float x) {
  float e = __expf(2.0f * x);
  return 1.0f - __fdividef(2.0f, e + 1.0f);
}

// packed f32x2 -> bf16x2 (RNE), single VALU op (numerics verified R12)
__device__ __forceinline__ unsigned cvt_pk_bf16(float lo, float hi) {
  unsigned r;
  asm("v_cvt_pk_bf16_f32 %0, %1, %2" : "=v"(r) : "v"(lo), "v"(hi));
  return r;
}

// ---------------------------------------------------------------- convert W,U -> bf16
__global__ __launch_bounds__(256) void convert_wu(
    const float* __restrict__ W, const float* __restrict__ U,
    short* __restrict__ Wb, short* __restrict__ Ub) {
  int i = blockIdx.x * 256 + threadIdx.x;
  if (i < 65536) {
    f32x4 v = ((const f32x4*)W)[i];
    short4_t s;
    s.x = f2bf(v.x); s.y = f2bf(v.y); s.z = f2bf(v.z); s.w = f2bf(v.w);
    ((short4_t*)Wb)[i] = s;
  } else if (i < 98304) {
    int k = i - 65536;
    f32x4 v = ((const f32x4*)U)[k];
    short4_t s;
    s.x = f2bf(v.x); s.y = f2bf(v.y); s.z = f2bf(v.z); s.w = f2bf(v.w);
    ((short4_t*)Ub)[k] = s;
  }
}

// ---------------------------------------------------------------- xu = x @ U^T  (bf16 MFMA)
__global__ __launch_bounds__(256) void xu_gemm(
    const float* __restrict__ x, const short* __restrict__ Ub,
    float* __restrict__ out) {
  __shared__ __attribute__((aligned(16))) short a_lds[128][272];
  __shared__ __attribute__((aligned(16))) short b_lds[128][272];
  const int tid = threadIdx.x;
  const int mb = blockIdx.x >> 2;
  const int nb = blockIdx.x & 3;

  const float* xb = x + (size_t)mb * (128 * 256);
  for (int c = 0; c < 32; ++c) {
    int idx = c * 256 + tid;
    int r = idx >> 6, c4 = idx & 63;
    f32x4 v = ((const f32x4*)xb)[idx];
    short4_t s;
    s.x = f2bf(v.x); s.y = f2bf(v.y); s.z = f2bf(v.z); s.w = f2bf(v.w);
    *(short4_t*)&a_lds[r][c4 * 4] = s;
  }
  const short* ub = Ub + nb * (128 * 256);
  for (int c = 0; c < 16; ++c) {
    int idx = c * 256 + tid;
    int r = idx >> 5, ch = idx & 31;
    *(short8*)&b_lds[r][ch * 8] = ((const short8*)ub)[idx];
  }
  __syncthreads();

  const int lane = tid & 63, wave = tid >> 6;
  const int wr = wave >> 1, wc = wave & 1;
  const int lr = lane & 15, lk = lane >> 4;
  const f32x4 zero = {0.f, 0.f, 0.f, 0.f};
  f32x4 acc[4][4];
  #pragma unroll
  for (int mt = 0; mt < 4; ++mt)
    #pragma unroll
    for (int nt = 0; nt < 4; ++nt) acc[mt][nt] = zero;

  #pragma unroll
  for (int kt = 0; kt < 8; ++kt) {
    const int k = kt * 32 + lk * 8;
    short8 a[4], b[4];
    #pragma unroll
    for (int mt = 0; mt < 4; ++mt)
      a[mt] = *(const short8*)&a_lds[wr * 64 + mt * 16 + lr][k];
    #pragma unroll
    for (int nt = 0; nt < 4; ++nt)
      b[nt] = *(const short8*)&b_lds[wc * 64 + nt * 16 + lr][k];
    #pragma unroll
    for (int mt = 0; mt < 4; ++mt)
      #pragma unroll
      for (int nt = 0; nt < 4; ++nt)
        acc[mt][nt] = __builtin_amdgcn_mfma_f32_16x16x32_bf16(a[mt], b[nt], acc[mt][nt], 0, 0, 0);
  }

  #pragma unroll
  for (int mt = 0; mt < 4; ++mt)
    #pragma unroll
    for (int nt = 0; nt < 4; ++nt)
      #pragma unroll
      for (int q = 0; q < 4; ++q) {
        int row = mb * 128 + wr * 64 + mt * 16 + lk * 4 + q;
        int col = nb * 128 + wc * 64 + nt * 16 + lr;
        out[(size_t)row * 512 + col] = acc[mt][nt][q];
      }
}

// ---------------------------------------------------------------- recurrence scan
// R7 champion structure (4 blocks x 512 thr, plain __syncthreads — R12 proved
// asm barriers collapse the compiler's load pipeline) with two deltas:
//  (1) a_lds DOUBLE-BUFFERED -> ONE barrier per step (stage into buf[t&1],
//      read after the barrier; next iter stages the other buffer, so the
//      WAR hazard that needed barrier #2 is gone structurally).
//  (2) xu[t+1] prefetch issued at the START of the MFMA phase (right after
//      acc <- xun copy) so L2/L3 latency hides under 16 kt of MFMA.
// W split: kt0..1 in 32 pinned VGPRs, kt2..4 in LDS (104-short rows: 16B
// aligned, bank-advance 20 -> conflict-free), kt5..15 streamed (352KB/step,
// depth-2 rotation). LDS total 139.8KB.
__global__ __launch_bounds__(512, 2) void rnn_scan(
    const short* __restrict__ Wb, float* __restrict__ out) {
  __shared__ __attribute__((aligned(16))) short w_lds[512][104];   // k 64..160
  __shared__ __attribute__((aligned(16))) short a_lds[2][16][520]; // tanh(h) x2
  const int tid = threadIdx.x;
  const int blk = blockIdx.x;
  const int lane = tid & 63, wave = tid >> 6;
  const int j0 = wave * 64;
  const int lr = lane & 15, lk = lane >> 4;

  // register-resident W: k in [0,64), this wave's 64 j-cols. 32 VGPRs, pinned.
  short8 wreg[4][2];
  #pragma unroll
  for (int jt = 0; jt < 4; ++jt) {
    const short* wrow = Wb + (j0 + jt * 16 + lr) * 512 + lk * 8;
    #pragma unroll
    for (int kt = 0; kt < 2; ++kt) {
      wreg[jt][kt] = *(const short8*)(wrow + kt * 32);
      asm volatile("" : "+v"(wreg[jt][kt]));   // block remat/sink
    }
  }

  // stream row pointers (loop-invariant; kt offsets fold to immediates)
  const short* pj[4];
  #pragma unroll
  for (int jt = 0; jt < 4; ++jt)
    pj[jt] = Wb + (j0 + jt * 16 + lr) * 512 + lk * 8;

  // LDS-resident W slice (k in [64,160)): thread tid owns row tid, 12 chunks
  #pragma unroll
  for (int c = 0; c < 12; ++c)
    *(short8*)&w_lds[tid][c * 8] = *(const short8*)(Wb + tid * 512 + 64 + c * 8);

  float h[4][4];
  #pragma unroll
  for (int jt = 0; jt < 4; ++jt)
    #pragma unroll
    for (int q = 0; q < 4; ++q) h[jt][q] = 0.f;

  const size_t base = (size_t)(blk * 16 + lk * 4) * 524288 + j0 + lr;
  __syncthreads();   // prologue sync (covers w_lds staging)

  // prefetch xu[t=0]
  float xun[4][4];
  {
    const float* p = out + base;
    #pragma unroll
    for (int jt = 0; jt < 4; ++jt)
      #pragma unroll
      for (int q = 0; q < 4; ++q)
        xun[jt][q] = p[(size_t)q * 524288 + jt * 16];
  }

  for (int t = 0; t < 1024; ++t) {
    const int pb = t & 1;
    // A = tanh(h) -> bf16 staging into buf[pb] (paired cvt_pk)
    #pragma unroll
    for (int jt = 0; jt < 4; ++jt)
      #pragma unroll
      for (int p = 0; p < 2; ++p) {
        unsigned pk = cvt_pk_bf16(tanh_fast(h[jt][2 * p]), tanh_fast(h[jt][2 * p + 1]));
        a_lds[pb][lk * 4 + 2 * p][j0 + jt * 16 + lr] = (short)(pk & 0xffffu);
        a_lds[pb][lk * 4 + 2 * p + 1][j0 + jt * 16 + lr] = (short)(pk >> 16);
      }
    __syncthreads();   // the ONLY barrier per step

    // acc <- xu_t (register copy), then issue xu[t+1] prefetch immediately
    // (completes during the MFMA phase)
    f32x4 acc[4];
    #pragma unroll
    for (int jt = 0; jt < 4; ++jt)
      #pragma unroll
      for (int q = 0; q < 4; ++q) acc[jt][q] = xun[jt][q];
    {
      int tn = t + 1; if (tn > 1023) tn = 1023;
      const float* pn = out + base + (size_t)tn * 512;
      #pragma unroll
      for (int jt = 0; jt < 4; ++jt)
        #pragma unroll
        for (int q = 0; q < 4; ++q)
          xun[jt][q] = pn[(size_t)q * 524288 + jt * 16];
    }

    // issue first two stream groups (kt 5,6)
    short8 s0[4], s1[4];
    #pragma unroll
    for (int jt = 0; jt < 4; ++jt) s0[jt] = *(const short8*)(pj[jt] + 5 * 32);
    #pragma unroll
    for (int jt = 0; jt < 4; ++jt) s1[jt] = *(const short8*)(pj[jt] + 6 * 32);

    // kt 0..1: register W
    #pragma unroll
    for (int kt = 0; kt < 2; ++kt) {
      short8 a8 = *(const short8*)&a_lds[pb][lr][kt * 32 + lk * 8];
      #pragma unroll
      for (int jt = 0; jt < 4; ++jt)
        acc[jt] = __builtin_amdgcn_mfma_f32_16x16x32_bf16(a8, wreg[jt][kt], acc[jt], 0, 0, 0);
    }
    // kt 2..4: LDS W
    #pragma unroll
    for (int kt = 2; kt < 5; ++kt) {
      short8 a8 = *(const short8*)&a_lds[pb][lr][kt * 32 + lk * 8];
      #pragma unroll
      for (int jt = 0; jt < 4; ++jt) {
        short8 b = *(const short8*)&w_lds[j0 + jt * 16 + lr][(kt - 2) * 32 + lk * 8];
        acc[jt] = __builtin_amdgcn_mfma_f32_16x16x32_bf16(a8, b, acc[jt], 0, 0, 0);
      }
    }
    // kt 5..15: streamed W, depth-2 rotation (kt-5 even -> s0, odd -> s1)
    #pragma unroll
    for (int kt = 5; kt < 16; ++kt) {
      short8 a8 = *(const short8*)&a_lds[pb][lr][kt * 32 + lk * 8];
      if (((kt - 5) & 1) == 0) {
        #pragma unroll
        for (int jt = 0; jt < 4; ++jt)
          acc[jt] = __builtin_amdgcn_mfma_f32_16x16x32_bf16(a8, s0[jt], acc[jt], 0, 0, 0);
        if (kt + 2 < 16) {
          #pragma unroll
          for (int jt = 0; jt < 4; ++jt)
            s0[jt] = *(const short8*)(pj[jt] + (kt + 2) * 32);
        }
      } else {
        #pragma unroll
        for (int jt = 0; jt < 4; ++jt)
          acc[jt] = __builtin_amdgcn_mfma_f32_16x16x32_bf16(a8, s1[jt], acc[jt], 0, 0, 0);
        if (kt + 2 < 16) {
          #pragma unroll
          for (int jt = 0; jt < 4; ++jt)
            s1[jt] = *(const short8*)(pj[jt] + (kt + 2) * 32);
        }
      }
    }

    // h' = 0.9*h + 0.1*acc; store in place over xu[t]
    float* po = out + base + (size_t)t * 512;
    #pragma unroll
    for (int jt = 0; jt < 4; ++jt)
      #pragma unroll
      for (int q = 0; q < 4; ++q) {
        float v = 0.9f * h[jt][q] + 0.1f * acc[jt][q];
        h[jt][q] = v;
        po[(size_t)q * 524288 + jt * 16] = v;
      }
    // no second barrier: next iteration stages the OTHER a_lds buffer
  }
}

// ----------------------------------------------------------------
extern "C" void kernel_launch(void* const* d_in, const int* in_sizes, int n_in,
                              void* d_out, int out_size, void* d_ws, size_t ws_size,
                              hipStream_t stream) {
  (void)in_sizes; (void)n_in; (void)out_size; (void)ws_size;
  const float* x = (const float*)d_in[0];
  const float* W = (const float*)d_in[1];
  const float* U = (const float*)d_in[2];
  float* out = (float*)d_out;
  short* Wb = (short*)d_ws;
  short* Ub = Wb + 512 * 512;

  convert_wu<<<384, 256, 0, stream>>>(W, U, Wb, Ub);
  xu_gemm<<<2048, 256, 0, stream>>>(x, Ub, out);
  rnn_scan<<<4, 512, 0, stream>>>(Wb, out);
}

// Round 14
// 4051.474 us; speedup vs baseline: 2.8756x; 2.8756x over previous
//
#include <hip/hip_runtime.h>

typedef __attribute__((ext_vector_type(4))) float f32x4;
typedef __attribute__((ext_vector_type(8))) short short8;
typedef __attribute__((ext_vector_type(4))) short short4_t;

__device__ __forceinline__ short f2bf(float f) {
  unsigned u = __float_as_uint(f);
  u += 0x7fffu + ((u >> 16) & 1u);   // round-to-nearest-even
  return (short)(u >> 16);
}

__device__ __forceinline__ float tanh_fast(float x) {
  float e = __expf(2.0f * x);
  return 1.0f - __fdividef(2.0f, e + 1.0f);
}

// ---------------------------------------------------------------- convert W,U -> bf16
__global__ __launch_bounds__(256) void convert_wu(
    const float* __restrict__ W, const float* __restrict__ U,
    short* __restrict__ Wb, short* __restrict__ Ub) {
  int i = blockIdx.x * 256 + threadIdx.x;
  if (i < 65536) {
    f32x4 v = ((const f32x4*)W)[i];
    short4_t s;
    s.x = f2bf(v.x); s.y = f2bf(v.y); s.z = f2bf(v.z); s.w = f2bf(v.w);
    ((short4_t*)Wb)[i] = s;
  } else if (i < 98304) {
    int k = i - 65536;
    f32x4 v = ((const f32x4*)U)[k];
    short4_t s;
    s.x = f2bf(v.x); s.y = f2bf(v.y); s.z = f2bf(v.z); s.w = f2bf(v.w);
    ((short4_t*)Ub)[k] = s;
  }
}

// ---------------------------------------------------------------- xu = x @ U^T  (bf16 MFMA)
__global__ __launch_bounds__(256) void xu_gemm(
    const float* __restrict__ x, const short* __restrict__ Ub,
    float* __restrict__ out) {
  __shared__ __attribute__((aligned(16))) short a_lds[128][272];
  __shared__ __attribute__((aligned(16))) short b_lds[128][272];
  const int tid = threadIdx.x;
  const int mb = blockIdx.x >> 2;
  const int nb = blockIdx.x & 3;

  const float* xb = x + (size_t)mb * (128 * 256);
  for (int c = 0; c < 32; ++c) {
    int idx = c * 256 + tid;
    int r = idx >> 6, c4 = idx & 63;
    f32x4 v = ((const f32x4*)xb)[idx];
    short4_t s;
    s.x = f2bf(v.x); s.y = f2bf(v.y); s.z = f2bf(v.z); s.w = f2bf(v.w);
    *(short4_t*)&a_lds[r][c4 * 4] = s;
  }
  const short* ub = Ub + nb * (128 * 256);
  for (int c = 0; c < 16; ++c) {
    int idx = c * 256 + tid;
    int r = idx >> 5, ch = idx & 31;
    *(short8*)&b_lds[r][ch * 8] = ((const short8*)ub)[idx];
  }
  __syncthreads();

  const int lane = tid & 63, wave = tid >> 6;
  const int wr = wave >> 1, wc = wave & 1;
  const int lr = lane & 15, lk = lane >> 4;
  const f32x4 zero = {0.f, 0.f, 0.f, 0.f};
  f32x4 acc[4][4];
  #pragma unroll
  for (int mt = 0; mt < 4; ++mt)
    #pragma unroll
    for (int nt = 0; nt < 4; ++nt) acc[mt][nt] = zero;

  #pragma unroll
  for (int kt = 0; kt < 8; ++kt) {
    const int k = kt * 32 + lk * 8;
    short8 a[4], b[4];
    #pragma unroll
    for (int mt = 0; mt < 4; ++mt)
      a[mt] = *(const short8*)&a_lds[wr * 64 + mt * 16 + lr][k];
    #pragma unroll
    for (int nt = 0; nt < 4; ++nt)
      b[nt] = *(const short8*)&b_lds[wc * 64 + nt * 16 + lr][k];
    #pragma unroll
    for (int mt = 0; mt < 4; ++mt)
      #pragma unroll
      for (int nt = 0; nt < 4; ++nt)
        acc[mt][nt] = __builtin_amdgcn_mfma_f32_16x16x32_bf16(a[mt], b[nt], acc[mt][nt], 0, 0, 0);
  }

  #pragma unroll
  for (int mt = 0; mt < 4; ++mt)
    #pragma unroll
    for (int nt = 0; nt < 4; ++nt)
      #pragma unroll
      for (int q = 0; q < 4; ++q) {
        int row = mb * 128 + wr * 64 + mt * 16 + lk * 4 + q;
        int col = nb * 128 + wc * 64 + nt * 16 + lr;
        out[(size_t)row * 512 + col] = acc[mt][nt][q];
      }
}

// ---------------------------------------------------------------- recurrence scan
// R7 champion structure with R13's two STRUCTURAL deltas, expressed in plain
// C only (R12/R13 lesson: ANY inline asm in the loop body — lds_barrier or
// v_cvt_pk — fragments the scheduler region, kills the compiler's stream-load
// pipelining: VGPR 120->88, 3.0->10.7/11.6 ms; m240 warned this for cvt_pk):
//  (1) a_lds DOUBLE-BUFFERED -> ONE __syncthreads per step (stage buf[t&1],
//      read after barrier; next iter stages the other buffer).
//  (2) xu[t+1] prefetch issued right after acc <- xun copy, so its latency
//      hides under the 16-kt MFMA phase.
// W split: kt0..1 in 32 pinned VGPRs, kt2..4 in LDS (104-short rows, 2-way
// bank alias = free), kt5..15 streamed from L2 (352KB/step, depth-2 rotation).
__global__ __launch_bounds__(512, 2) void rnn_scan(
    const short* __restrict__ Wb, float* __restrict__ out) {
  __shared__ __attribute__((aligned(16))) short w_lds[512][104];   // k 64..160
  __shared__ __attribute__((aligned(16))) short a_lds[2][16][520]; // tanh(h) x2
  const int tid = threadIdx.x;
  const int blk = blockIdx.x;
  const int lane = tid & 63, wave = tid >> 6;
  const int j0 = wave * 64;
  const int lr = lane & 15, lk = lane >> 4;

  // register-resident W: k in [0,64), this wave's 64 j-cols. 32 VGPRs, pinned.
  short8 wreg[4][2];
  #pragma unroll
  for (int jt = 0; jt < 4; ++jt) {
    const short* wrow = Wb + (j0 + jt * 16 + lr) * 512 + lk * 8;
    #pragma unroll
    for (int kt = 0; kt < 2; ++kt) {
      wreg[jt][kt] = *(const short8*)(wrow + kt * 32);
      asm volatile("" : "+v"(wreg[jt][kt]));   // prologue-only pin (proven R7)
    }
  }

  // stream row pointers (loop-invariant; kt offsets fold to immediates)
  const short* pj[4];
  #pragma unroll
  for (int jt = 0; jt < 4; ++jt)
    pj[jt] = Wb + (j0 + jt * 16 + lr) * 512 + lk * 8;

  // LDS-resident W slice (k in [64,160)): thread tid owns row tid, 12 chunks
  #pragma unroll
  for (int c = 0; c < 12; ++c)
    *(short8*)&w_lds[tid][c * 8] = *(const short8*)(Wb + tid * 512 + 64 + c * 8);

  float h[4][4];
  #pragma unroll
  for (int jt = 0; jt < 4; ++jt)
    #pragma unroll
    for (int q = 0; q < 4; ++q) h[jt][q] = 0.f;

  const size_t base = (size_t)(blk * 16 + lk * 4) * 524288 + j0 + lr;
  __syncthreads();   // prologue sync (covers w_lds staging)

  // prefetch xu[t=0]
  float xun[4][4];
  {
    const float* p = out + base;
    #pragma unroll
    for (int jt = 0; jt < 4; ++jt)
      #pragma unroll
      for (int q = 0; q < 4; ++q)
        xun[jt][q] = p[(size_t)q * 524288 + jt * 16];
  }

  for (int t = 0; t < 1024; ++t) {
    const int pb = t & 1;
    // A = tanh(h) -> bf16 staging into buf[pb] (plain scalar stores)
    #pragma unroll
    for (int jt = 0; jt < 4; ++jt)
      #pragma unroll
      for (int q = 0; q < 4; ++q)
        a_lds[pb][lk * 4 + q][j0 + jt * 16 + lr] = f2bf(tanh_fast(h[jt][q]));
    __syncthreads();   // the ONLY barrier per step

    // acc <- xu_t (register copy), then issue xu[t+1] prefetch immediately
    f32x4 acc[4];
    #pragma unroll
    for (int jt = 0; jt < 4; ++jt)
      #pragma unroll
      for (int q = 0; q < 4; ++q) acc[jt][q] = xun[jt][q];
    {
      int tn = t + 1; if (tn > 1023) tn = 1023;
      const float* pn = out + base + (size_t)tn * 512;
      #pragma unroll
      for (int jt = 0; jt < 4; ++jt)
        #pragma unroll
        for (int q = 0; q < 4; ++q)
          xun[jt][q] = pn[(size_t)q * 524288 + jt * 16];
    }

    // issue first two stream groups (kt 5,6)
    short8 s0[4], s1[4];
    #pragma unroll
    for (int jt = 0; jt < 4; ++jt) s0[jt] = *(const short8*)(pj[jt] + 5 * 32);
    #pragma unroll
    for (int jt = 0; jt < 4; ++jt) s1[jt] = *(const short8*)(pj[jt] + 6 * 32);

    // kt 0..1: register W
    #pragma unroll
    for (int kt = 0; kt < 2; ++kt) {
      short8 a8 = *(const short8*)&a_lds[pb][lr][kt * 32 + lk * 8];
      #pragma unroll
      for (int jt = 0; jt < 4; ++jt)
        acc[jt] = __builtin_amdgcn_mfma_f32_16x16x32_bf16(a8, wreg[jt][kt], acc[jt], 0, 0, 0);
    }
    // kt 2..4: LDS W
    #pragma unroll
    for (int kt = 2; kt < 5; ++kt) {
      short8 a8 = *(const short8*)&a_lds[pb][lr][kt * 32 + lk * 8];
      #pragma unroll
      for (int jt = 0; jt < 4; ++jt) {
        short8 b = *(const short8*)&w_lds[j0 + jt * 16 + lr][(kt - 2) * 32 + lk * 8];
        acc[jt] = __builtin_amdgcn_mfma_f32_16x16x32_bf16(a8, b, acc[jt], 0, 0, 0);
      }
    }
    // kt 5..15: streamed W, depth-2 rotation (kt-5 even -> s0, odd -> s1)
    #pragma unroll
    for (int kt = 5; kt < 16; ++kt) {
      short8 a8 = *(const short8*)&a_lds[pb][lr][kt * 32 + lk * 8];
      if (((kt - 5) & 1) == 0) {
        #pragma unroll
        for (int jt = 0; jt < 4; ++jt)
          acc[jt] = __builtin_amdgcn_mfma_f32_16x16x32_bf16(a8, s0[jt], acc[jt], 0, 0, 0);
        if (kt + 2 < 16) {
          #pragma unroll
          for (int jt = 0; jt < 4; ++jt)
            s0[jt] = *(const short8*)(pj[jt] + (kt + 2) * 32);
        }
      } else {
        #pragma unroll
        for (int jt = 0; jt < 4; ++jt)
          acc[jt] = __builtin_amdgcn_mfma_f32_16x16x32_bf16(a8, s1[jt], acc[jt], 0, 0, 0);
        if (kt + 2 < 16) {
          #pragma unroll
          for (int jt = 0; jt < 4; ++jt)
            s1[jt] = *(const short8*)(pj[jt] + (kt + 2) * 32);
        }
      }
    }

    // h' = 0.9*h + 0.1*acc; store in place over xu[t]
    float* po = out + base + (size_t)t * 512;
    #pragma unroll
    for (int jt = 0; jt < 4; ++jt)
      #pragma unroll
      for (int q = 0; q < 4; ++q) {
        float v = 0.9f * h[jt][q] + 0.1f * acc[jt][q];
        h[jt][q] = v;
        po[(size_t)q * 524288 + jt * 16] = v;
      }
    // no second barrier: next iteration stages the OTHER a_lds buffer
  }
}

// ----------------------------------------------------------------
extern "C" void kernel_launch(void* const* d_in, const int* in_sizes, int n_in,
                              void* d_out, int out_size, void* d_ws, size_t ws_size,
                              hipStream_t stream) {
  (void)in_sizes; (void)n_in; (void)out_size; (void)ws_size;
  const float* x = (const float*)d_in[0];
  const float* W = (const float*)d_in[1];
  const float* U = (const float*)d_in[2];
  float* out = (float*)d_out;
  short* Wb = (short*)d_ws;
  short* Ub = Wb + 512 * 512;

  convert_wu<<<384, 256, 0, stream>>>(W, U, Wb, Ub);
  xu_gemm<<<2048, 256, 0, stream>>>(x, Ub, out);
  rnn_scan<<<4, 512, 0, stream>>>(Wb, out);
}

// Round 15
// 3309.202 us; speedup vs baseline: 3.5206x; 1.2243x over previous
//
#include <hip/hip_runtime.h>

typedef __attribute__((ext_vector_type(4))) float f32x4;
typedef __attribute__((ext_vector_type(8))) short short8;
typedef __attribute__((ext_vector_type(4))) short short4_t;

__device__ __forceinline__ short f2bf(float f) {
  unsigned u = __float_as_uint(f);
  u += 0x7fffu + ((u >> 16) & 1u);   // round-to-nearest-even
  return (short)(u >> 16);
}

__device__ __forceinline__ float tanh_fast(float x) {
  float e = __expf(2.0f * x);
  return 1.0f - __fdividef(2.0f, e + 1.0f);
}

// ---------------------------------------------------------------- convert W,U -> bf16
__global__ __launch_bounds__(256) void convert_wu(
    const float* __restrict__ W, const float* __restrict__ U,
    short* __restrict__ Wb, short* __restrict__ Ub) {
  int i = blockIdx.x * 256 + threadIdx.x;
  if (i < 65536) {
    f32x4 v = ((const f32x4*)W)[i];
    short4_t s;
    s.x = f2bf(v.x); s.y = f2bf(v.y); s.z = f2bf(v.z); s.w = f2bf(v.w);
    ((short4_t*)Wb)[i] = s;
  } else if (i < 98304) {
    int k = i - 65536;
    f32x4 v = ((const f32x4*)U)[k];
    short4_t s;
    s.x = f2bf(v.x); s.y = f2bf(v.y); s.z = f2bf(v.z); s.w = f2bf(v.w);
    ((short4_t*)Ub)[k] = s;
  }
}

// ---------------------------------------------------------------- xu = x @ U^T  (bf16 MFMA)
__global__ __launch_bounds__(256) void xu_gemm(
    const float* __restrict__ x, const short* __restrict__ Ub,
    float* __restrict__ out) {
  __shared__ __attribute__((aligned(16))) short a_lds[128][272];
  __shared__ __attribute__((aligned(16))) short b_lds[128][272];
  const int tid = threadIdx.x;
  const int mb = blockIdx.x >> 2;
  const int nb = blockIdx.x & 3;

  const float* xb = x + (size_t)mb * (128 * 256);
  for (int c = 0; c < 32; ++c) {
    int idx = c * 256 + tid;
    int r = idx >> 6, c4 = idx & 63;
    f32x4 v = ((const f32x4*)xb)[idx];
    short4_t s;
    s.x = f2bf(v.x); s.y = f2bf(v.y); s.z = f2bf(v.z); s.w = f2bf(v.w);
    *(short4_t*)&a_lds[r][c4 * 4] = s;
  }
  const short* ub = Ub + nb * (128 * 256);
  for (int c = 0; c < 16; ++c) {
    int idx = c * 256 + tid;
    int r = idx >> 5, ch = idx & 31;
    *(short8*)&b_lds[r][ch * 8] = ((const short8*)ub)[idx];
  }
  __syncthreads();

  const int lane = tid & 63, wave = tid >> 6;
  const int wr = wave >> 1, wc = wave & 1;
  const int lr = lane & 15, lk = lane >> 4;
  const f32x4 zero = {0.f, 0.f, 0.f, 0.f};
  f32x4 acc[4][4];
  #pragma unroll
  for (int mt = 0; mt < 4; ++mt)
    #pragma unroll
    for (int nt = 0; nt < 4; ++nt) acc[mt][nt] = zero;

  #pragma unroll
  for (int kt = 0; kt < 8; ++kt) {
    const int k = kt * 32 + lk * 8;
    short8 a[4], b[4];
    #pragma unroll
    for (int mt = 0; mt < 4; ++mt)
      a[mt] = *(const short8*)&a_lds[wr * 64 + mt * 16 + lr][k];
    #pragma unroll
    for (int nt = 0; nt < 4; ++nt)
      b[nt] = *(const short8*)&b_lds[wc * 64 + nt * 16 + lr][k];
    #pragma unroll
    for (int mt = 0; mt < 4; ++mt)
      #pragma unroll
      for (int nt = 0; nt < 4; ++nt)
        acc[mt][nt] = __builtin_amdgcn_mfma_f32_16x16x32_bf16(a[mt], b[nt], acc[mt][nt], 0, 0, 0);
  }

  #pragma unroll
  for (int mt = 0; mt < 4; ++mt)
    #pragma unroll
    for (int nt = 0; nt < 4; ++nt)
      #pragma unroll
      for (int q = 0; q < 4; ++q) {
        int row = mb * 128 + wr * 64 + mt * 16 + lk * 4 + q;
        int col = nb * 128 + wc * 64 + nt * 16 + lr;
        out[(size_t)row * 512 + col] = acc[mt][nt][q];
      }
}

// ---------------------------------------------------------------- recurrence scan
// EXACT R7 champion (4 blocks x 512 thr; W = kt0..1 in 32 pinned VGPRs,
// kt2..5 in LDS, kt6..15 streamed; two plain __syncthreads) + two surgical
// scheduling deltas, both plain C (R12/R13: no asm in loop body):
//  (1) CROSS-ITERATION STREAM ROTATION: s0/s1 are live across iterations;
//      kt14/kt15 refill them with next iteration's kt6/kt7 (loop-invariant
//      addresses). LLVM cannot hoist loads across a convergent barrier, so
//      this hoisting must be in source. Kills the post-barrier L1 idle window.
//  (2) DEFERRED h-STORE: iter t stores h_t (still in regs) to out slot t-1
//      right after bar1; the store completes under the MFMA/stream phase, so
//      bar2's vmcnt(0) drain no longer eats a store round-trip.
__global__ __launch_bounds__(512, 2) void rnn_scan(
    const short* __restrict__ Wb, float* __restrict__ out) {
  __shared__ __attribute__((aligned(16))) short w_lds[512][136];  // k 64..192
  __shared__ __attribute__((aligned(16))) short a_lds[16][520];   // tanh(h) bf16
  const int tid = threadIdx.x;
  const int blk = blockIdx.x;
  const int lane = tid & 63, wave = tid >> 6;
  const int j0 = wave * 64;
  const int lr = lane & 15, lk = lane >> 4;

  // register-resident W: k in [0,64), this wave's 64 j-cols. 32 VGPRs, pinned.
  short8 wreg[4][2];
  #pragma unroll
  for (int jt = 0; jt < 4; ++jt) {
    const short* wrow = Wb + (j0 + jt * 16 + lr) * 512 + lk * 8;
    #pragma unroll
    for (int kt = 0; kt < 2; ++kt) {
      wreg[jt][kt] = *(const short8*)(wrow + kt * 32);
      asm volatile("" : "+v"(wreg[jt][kt]));   // prologue-only pin (proven R7)
    }
  }

  // stream row pointers (loop-invariant; kt offsets fold to immediates)
  const short* pj[4];
  #pragma unroll
  for (int jt = 0; jt < 4; ++jt)
    pj[jt] = Wb + (j0 + jt * 16 + lr) * 512 + lk * 8;

  // LDS-resident W slice (k in [64,192)): 512 rows x 16 short8-chunks
  for (int c = 0; c < 16; ++c) {
    int idx = c * 512 + tid;
    int j = idx >> 4, ch = idx & 15;
    *(short8*)&w_lds[j][ch * 8] = *(const short8*)(Wb + j * 512 + 64 + ch * 8);
  }

  float h[4][4];
  #pragma unroll
  for (int jt = 0; jt < 4; ++jt)
    #pragma unroll
    for (int q = 0; q < 4; ++q) h[jt][q] = 0.f;

  const size_t base = (size_t)(blk * 16 + lk * 4) * 524288 + j0 + lr;
  __syncthreads();   // prologue sync (covers w_lds staging)

  f32x4 acc[4];
  // prologue: acc <- xu[t=0]; prime the stream rotation with kt6/kt7
  {
    const float* p = out + base;
    #pragma unroll
    for (int jt = 0; jt < 4; ++jt)
      #pragma unroll
      for (int q = 0; q < 4; ++q)
        acc[jt][q] = p[(size_t)q * 524288 + jt * 16];
  }
  short8 s0[4], s1[4];
  #pragma unroll
  for (int jt = 0; jt < 4; ++jt) s0[jt] = *(const short8*)(pj[jt] + 6 * 32);
  #pragma unroll
  for (int jt = 0; jt < 4; ++jt) s1[jt] = *(const short8*)(pj[jt] + 7 * 32);

  for (int t = 0; t < 1024; ++t) {
    // A = tanh(h_t) -> bf16 staging
    #pragma unroll
    for (int jt = 0; jt < 4; ++jt)
      #pragma unroll
      for (int q = 0; q < 4; ++q)
        a_lds[lk * 4 + q][j0 + jt * 16 + lr] = f2bf(tanh_fast(h[jt][q]));
    __syncthreads();   // bar1

    // deferred store: h (= h_t, output slot t-1) — completes under MFMA phase
    if (t > 0) {
      float* pd = out + base + (size_t)(t - 1) * 512;
      #pragma unroll
      for (int jt = 0; jt < 4; ++jt)
        #pragma unroll
        for (int q = 0; q < 4; ++q)
          pd[(size_t)q * 524288 + jt * 16] = h[jt][q];
    }

    // kt 0..1: register W
    #pragma unroll
    for (int kt = 0; kt < 2; ++kt) {
      short8 a8 = *(const short8*)&a_lds[lr][kt * 32 + lk * 8];
      #pragma unroll
      for (int jt = 0; jt < 4; ++jt)
        acc[jt] = __builtin_amdgcn_mfma_f32_16x16x32_bf16(a8, wreg[jt][kt], acc[jt], 0, 0, 0);
    }
    // kt 2..5: LDS W
    #pragma unroll
    for (int kt = 2; kt < 6; ++kt) {
      short8 a8 = *(const short8*)&a_lds[lr][kt * 32 + lk * 8];
      #pragma unroll
      for (int jt = 0; jt < 4; ++jt) {
        short8 b = *(const short8*)&w_lds[j0 + jt * 16 + lr][(kt - 2) * 32 + lk * 8];
        acc[jt] = __builtin_amdgcn_mfma_f32_16x16x32_bf16(a8, b, acc[jt], 0, 0, 0);
      }
    }
    // kt 6..15: streamed W, depth-2 rotation; kt14/kt15 refill NEXT
    // iteration's kt6/kt7 (same addresses — loop-invariant)
    #pragma unroll
    for (int kt = 6; kt < 16; ++kt) {
      short8 a8 = *(const short8*)&a_lds[lr][kt * 32 + lk * 8];
      const int nk = (kt + 2 < 16) ? (kt + 2) : (kt + 2 - 10);   // 16->6, 17->7
      if ((kt & 1) == 0) {
        #pragma unroll
        for (int jt = 0; jt < 4; ++jt)
          acc[jt] = __builtin_amdgcn_mfma_f32_16x16x32_bf16(a8, s0[jt], acc[jt], 0, 0, 0);
        #pragma unroll
        for (int jt = 0; jt < 4; ++jt)
          s0[jt] = *(const short8*)(pj[jt] + nk * 32);
      } else {
        #pragma unroll
        for (int jt = 0; jt < 4; ++jt)
          acc[jt] = __builtin_amdgcn_mfma_f32_16x16x32_bf16(a8, s1[jt], acc[jt], 0, 0, 0);
        #pragma unroll
        for (int jt = 0; jt < 4; ++jt)
          s1[jt] = *(const short8*)(pj[jt] + nk * 32);
      }
    }

    // h <- 0.9*h + 0.1*acc  (NO store here — deferred to next iteration)
    #pragma unroll
    for (int jt = 0; jt < 4; ++jt)
      #pragma unroll
      for (int q = 0; q < 4; ++q)
        h[jt][q] = 0.9f * h[jt][q] + 0.1f * acc[jt][q];
    __syncthreads();   // bar2 (a_lds WAR; drain is cheap now)

    // tail: prefetch next step's xu into acc (flies across loop-back + bar1)
    int tn = t + 1; if (tn > 1023) tn = 1023;
    const float* pn = out + base + (size_t)tn * 512;
    #pragma unroll
    for (int jt = 0; jt < 4; ++jt)
      #pragma unroll
      for (int q = 0; q < 4; ++q)
        acc[jt][q] = pn[(size_t)q * 524288 + jt * 16];
  }

  // epilogue: store h_1024 to out[1023]
  {
    float* pd = out + base + (size_t)1023 * 512;
    #pragma unroll
    for (int jt = 0; jt < 4; ++jt)
      #pragma unroll
      for (int q = 0; q < 4; ++q)
        pd[(size_t)q * 524288 + jt * 16] = h[jt][q];
  }
}

// ----------------------------------------------------------------
extern "C" void kernel_launch(void* const* d_in, const int* in_sizes, int n_in,
                              void* d_out, int out_size, void* d_ws, size_t ws_size,
                              hipStream_t stream) {
  (void)in_sizes; (void)n_in; (void)out_size; (void)ws_size;
  const float* x = (const float*)d_in[0];
  const float* W = (const float*)d_in[1];
  const float* U = (const float*)d_in[2];
  float* out = (float*)d_out;
  short* Wb = (short*)d_ws;
  short* Ub = Wb + 512 * 512;

  convert_wu<<<384, 256, 0, stream>>>(W, U, Wb, Ub);
  xu_gemm<<<2048, 256, 0, stream>>>(x, Ub, out);
  rnn_scan<<<4, 512, 0, stream>>>(Wb, out);
}